// Round 18
// baseline (1331.640 us; speedup 1.0000x reference)
//
#include <hip/hip_runtime.h>
#include <hip/hip_bf16.h>
#include <stdint.h>

#define M_TOTAL 8192      // BATCH*SEQ
#define N_TOTAL 16384     // OUT_FEATURES
#define K_TOTAL 4096      // IN_FEATURES (== BLOCKSIZE -> absmax is per output row)

#define BM 256
#define BN 256
#define BK 64
#define NKT (K_TOTAL / BK)   // 64 K-tiles

using f32x16 = __attribute__((ext_vector_type(16))) float;
using bf16x8 = __attribute__((ext_vector_type(8))) short;

#define UNROLL _Pragma("unroll")

__device__ __forceinline__ unsigned short f2bf(float f) {
    union { float f; unsigned u; } v; v.f = f;
    unsigned r = v.u + 0x7fffu + ((v.u >> 16) & 1u);   // RNE
    return (unsigned short)(r >> 16);
}

__device__ __forceinline__ void gload_lds16(const void* g, void* l) {
    __builtin_amdgcn_global_load_lds(
        (const __attribute__((address_space(1))) unsigned int*)g,
        (__attribute__((address_space(3))) unsigned int*)l,
        16, 0, 0);
}

// ---------------- dequant W: wb[o*K+i] = bf16(code[q[o*K+i]] * absmax[o]) ----------
__global__ void dequant_w_kernel(const int* __restrict__ q,
                                 const float* __restrict__ am,
                                 const float* __restrict__ code,
                                 unsigned short* __restrict__ wb) {
    __shared__ float lc[256];
    if (threadIdx.x < 256) lc[threadIdx.x] = code[threadIdx.x];
    __syncthreads();
    const int total = (N_TOTAL / 4) * K_TOTAL;   // 16,777,216 int4 groups
    const int stride = gridDim.x * blockDim.x;
    for (int i = blockIdx.x * blockDim.x + threadIdx.x; i < total; i += stride) {
        int4 v = reinterpret_cast<const int4*>(q)[i];
        float a = am[i >> 10];                   // one quant block == one weight row
        ushort4 o;
        o.x = f2bf(lc[v.x & 255] * a);
        o.y = f2bf(lc[v.y & 255] * a);
        o.z = f2bf(lc[v.z & 255] * a);
        o.w = f2bf(lc[v.w & 255] * a);
        reinterpret_cast<ushort4*>(wb)[i] = o;
    }
}

// ---------------- convert x fp32 -> bf16 ----------------
__global__ void cvt_x_kernel(const float* __restrict__ x,
                             unsigned short* __restrict__ xb) {
    const int total = (M_TOTAL * K_TOTAL) / 4;
    const int stride = gridDim.x * blockDim.x;
    for (int i = blockIdx.x * blockDim.x + threadIdx.x; i < total; i += stride) {
        float4 v = reinterpret_cast<const float4*>(x)[i];
        ushort4 o;
        o.x = f2bf(v.x); o.y = f2bf(v.y); o.z = f2bf(v.z); o.w = f2bf(v.w);
        reinterpret_cast<ushort4*>(xb)[i] = o;
    }
}

// ---- GEMM 256x256x64: 4 waves x 128x128/wave, mfma 32x32x16, 2-buffer ----
// Wave grid 2x2 -> A,B each read only 2x from LDS (128 KB/K-tile vs 192 for
// 2x4): LDS floor drops below the MFMA floor -> MFMA-bound regime.
// LDS swizzle identical to r6-r17 (0 conflicts): row-major [256][64] bf16,
// 8 chunks/row; physical chunk = logical ^ (row&7); linear gload_lds dest +
// pre-swizzled per-lane global source (rule #21).
// A-frag (32x32x16): lane l holds A[row0 + (l&31)][k0 + (l>>5)*8 + j], j=0..7
//   (generalizes the session-verified 16x16x32 mapping row=l&15,k=(l>>4)*8+j).
// C/D (32x32): col = lane&31, row = (reg&3) + 8*(reg>>2) + 4*(lane>>5)
//   [guide m74/m101, HW-verified].
__global__ __launch_bounds__(256, 1) void gemm_bw_kernel(
        const unsigned short* __restrict__ A,   // [M][K] bf16
        const unsigned short* __restrict__ B,   // [N][K] bf16
        const float* __restrict__ bias,         // [N]
        float* __restrict__ C) {                // [M][N] f32
    __shared__ __align__(16) unsigned short sA[2][BM * BK];   // 2 x 32 KB
    __shared__ __align__(16) unsigned short sB[2][BN * BK];   // 2 x 32 KB

    // XCD swizzle (nwg = 2048, % 8 == 0 -> bijective)
    const int nwg = gridDim.x;
    const int bid = blockIdx.x;
    const int wg  = (bid & 7) * (nwg >> 3) + (bid >> 3);
    const int nbn = N_TOTAL / BN;            // 64
    const int brow = (wg / nbn) * BM;
    const int bcol = (wg % nbn) * BN;

    const int tid  = threadIdx.x;
    const int wid  = tid >> 6;               // 0..3
    const int lane = tid & 63;
    const int wm   = wid >> 1;               // 0..1  (M-waves)
    const int wn   = wid & 1;                // 0..1  (N-waves)

    // staging: linear LDS dest + pre-swizzled global source.
    // issue i covers rows [i*32 + wid*8, +8); lane -> row += lane>>3, chunk lane&7,
    // source chunk = (lane&7) ^ (lane>>3)  (= dest ^ (row&7)).
    const int srow = wid * 8 + (lane >> 3);
    const int scol = ((lane & 7) ^ (lane >> 3)) * 8;
    const unsigned short* Asrc = A + (long long)(brow + srow) * K_TOTAL + scol;
    const unsigned short* Bsrc = B + (long long)(bcol + srow) * K_TOTAL + scol;

    auto stA = [&](int i, int kt, int b) {
        gload_lds16(Asrc + (long long)(i * 32) * K_TOTAL + kt * BK,
                    &sA[b][(i * 32 + wid * 8) * BK]);
    };
    auto stB = [&](int i, int kt, int b) {
        gload_lds16(Bsrc + (long long)(i * 32) * K_TOTAL + kt * BK,
                    &sB[b][(i * 32 + wid * 8) * BK]);
    };
    auto stage_tile = [&](int kt, int b) {   // 16 issues/wave
        UNROLL for (int i = 0; i < 8; ++i) stA(i, kt, b);
        UNROLL for (int i = 0; i < 8; ++i) stB(i, kt, b);
    };

    const int l31 = lane & 31;
    const int l7  = lane & 7;
    const int kh  = lane >> 5;               // k-half 0..1

    f32x16 acc[4][4];
    UNROLL for (int mf = 0; mf < 4; ++mf)
        UNROLL for (int nf = 0; nf < 4; ++nf)
            UNROLL for (int r = 0; r < 16; ++r)
                acc[mf][nf][r] = 0.f;

    // one K-tile from buffer P (compile-time): 4 K-slices x {8 ds_read, 16 MFMA},
    // no internal barriers -> compiler interleaves reads/MFMA across slices.
#define COMPUTE(P)                                                                \
    UNROLL for (int ks = 0; ks < 4; ++ks) {                                       \
        bf16x8 af[4], bf[4];                                                      \
        UNROLL for (int mf = 0; mf < 4; ++mf) {                                   \
            const int row = wm * 128 + mf * 32 + l31;                             \
            af[mf] = *reinterpret_cast<const bf16x8*>(                            \
                &sA[P][row * BK + (((ks * 2 + kh) ^ l7) * 8)]);                   \
        }                                                                         \
        UNROLL for (int nf = 0; nf < 4; ++nf) {                                   \
            const int row = wn * 128 + nf * 32 + l31;                             \
            bf[nf] = *reinterpret_cast<const bf16x8*>(                            \
                &sB[P][row * BK + (((ks * 2 + kh) ^ l7) * 8)]);                   \
        }                                                                         \
        UNROLL for (int mf = 0; mf < 4; ++mf)                                     \
            UNROLL for (int nf = 0; nf < 4; ++nf)                                 \
                acc[mf][nf] = __builtin_amdgcn_mfma_f32_32x32x16_bf16(            \
                    af[mf], bf[nf], acc[mf][nf], 0, 0, 0);                        \
    }

    // tile-end gate: own-wave LDS drain (reads consumed by MFMA -> cheap) makes
    // next tile's stage into this buffer WAR-safe after the barrier; vmcnt(0)
    // waits the 16 stages issued at THIS tile's top (~2000 cyc slack -> cheap).
#define GATEV()                                                                   \
    asm volatile("s_waitcnt lgkmcnt(0) vmcnt(0)" ::: "memory");                   \
    __builtin_amdgcn_s_barrier();                                                 \
    asm volatile("" ::: "memory");

    // ---- prologue ----
    stage_tile(0, 0);
    GATEV();

    // ---- main loop: stage t+1 at tile top, compute t, gate ----
    for (int it = 0; it < NKT / 2 - 1; ++it) {    // 31 iterations
        stage_tile(2 * it + 1, 1);
        COMPUTE(0)                                 // tile 2it   (buf0)
        GATEV();
        stage_tile(2 * it + 2, 0);
        COMPUTE(1)                                 // tile 2it+1 (buf1)
        GATEV();
    }
    stage_tile(NKT - 1, 1);                        // tile 63 -> buf1
    COMPUTE(0)                                     // tile 62 (buf0)
    GATEV();
    COMPUTE(1)                                     // tile 63 (buf1)

    // ---- epilogue: 32x32 C/D layout: col=lane&31, row=(reg&3)+8*(reg>>2)+4*kh ----
    UNROLL for (int mf = 0; mf < 4; ++mf)
        UNROLL for (int nf = 0; nf < 4; ++nf) {
            const int col = bcol + wn * 128 + nf * 32 + l31;
            const float bv = bias[col];
            const long long rbase = (long long)brow + wm * 128 + mf * 32 + 4 * kh;
            UNROLL for (int r = 0; r < 16; ++r) {
                const long long row = rbase + (r & 3) + 8 * (r >> 2);
                C[row * N_TOTAL + col] = acc[mf][nf][r] + bv;
            }
        }
}

extern "C" void kernel_launch(void* const* d_in, const int* in_sizes, int n_in,
                              void* d_out, int out_size, void* d_ws, size_t ws_size,
                              hipStream_t stream) {
    const float* x      = (const float*)d_in[0];   // [4,2048,4096] f32
    const int*   wq     = (const int*)  d_in[1];   // [16384,4096] int32 idx
    const float* absmax = (const float*)d_in[2];   // [16384]
    const float* code   = (const float*)d_in[3];   // [256]
    const float* bias   = (const float*)d_in[4];   // [16384]
    float* out = (float*)d_out;                    // [4,2048,16384] f32

    unsigned short* wb = (unsigned short*)d_ws;                    // W bf16 134 MB
    unsigned short* xb = wb + (size_t)N_TOTAL * K_TOTAL;           // x bf16  67 MB

    dequant_w_kernel<<<2048, 256, 0, stream>>>(wq, absmax, code, wb);
    cvt_x_kernel   <<<2048, 256, 0, stream>>>(x, xb);

    dim3 grid((M_TOTAL / BM) * (N_TOTAL / BN));    // 32*64 = 2048 blocks
    gemm_bw_kernel<<<grid, 256, 0, stream>>>(xb, wb, bias, out);
}

// Round 19
// 1113.202 us; speedup vs baseline: 1.1962x; 1.1962x over previous
//
#include <hip/hip_runtime.h>
#include <hip/hip_bf16.h>
#include <stdint.h>

#define M_TOTAL 8192      // BATCH*SEQ
#define N_TOTAL 16384     // OUT_FEATURES
#define K_TOTAL 4096      // IN_FEATURES (== BLOCKSIZE -> absmax is per output row)

#define BM 256
#define BN 256
#define BK 64
#define NKT (K_TOTAL / BK)   // 64 K-tiles

using f32x4  = __attribute__((ext_vector_type(4))) float;
using bf16x8 = __attribute__((ext_vector_type(8))) short;

#define UNROLL _Pragma("unroll")

__device__ __forceinline__ unsigned short f2bf(float f) {
    union { float f; unsigned u; } v; v.f = f;
    unsigned r = v.u + 0x7fffu + ((v.u >> 16) & 1u);   // RNE
    return (unsigned short)(r >> 16);
}

__device__ __forceinline__ void gload_lds16(const void* g, void* l) {
    __builtin_amdgcn_global_load_lds(
        (const __attribute__((address_space(1))) unsigned int*)g,
        (__attribute__((address_space(3))) unsigned int*)l,
        16, 0, 0);
}

// ---------------- dequant W: wb[o*K+i] = bf16(code[q[o*K+i]] * absmax[o]) ----------
__global__ void dequant_w_kernel(const int* __restrict__ q,
                                 const float* __restrict__ am,
                                 const float* __restrict__ code,
                                 unsigned short* __restrict__ wb) {
    __shared__ float lc[256];
    if (threadIdx.x < 256) lc[threadIdx.x] = code[threadIdx.x];
    __syncthreads();
    const int total = (N_TOTAL / 4) * K_TOTAL;   // 16,777,216 int4 groups
    const int stride = gridDim.x * blockDim.x;
    for (int i = blockIdx.x * blockDim.x + threadIdx.x; i < total; i += stride) {
        int4 v = reinterpret_cast<const int4*>(q)[i];
        float a = am[i >> 10];                   // one quant block == one weight row
        ushort4 o;
        o.x = f2bf(lc[v.x & 255] * a);
        o.y = f2bf(lc[v.y & 255] * a);
        o.z = f2bf(lc[v.z & 255] * a);
        o.w = f2bf(lc[v.w & 255] * a);
        reinterpret_cast<ushort4*>(wb)[i] = o;
    }
}

// ---------------- convert x fp32 -> bf16 ----------------
__global__ void cvt_x_kernel(const float* __restrict__ x,
                             unsigned short* __restrict__ xb) {
    const int total = (M_TOTAL * K_TOTAL) / 4;
    const int stride = gridDim.x * blockDim.x;
    for (int i = blockIdx.x * blockDim.x + threadIdx.x; i < total; i += stride) {
        float4 v = reinterpret_cast<const float4*>(x)[i];
        ushort4 o;
        o.x = f2bf(v.x); o.y = f2bf(v.y); o.z = f2bf(v.z); o.w = f2bf(v.w);
        reinterpret_cast<ushort4*>(xb)[i] = o;
    }
}

// ---- GEMM 256x256x64: 2 phases/K-tile (r16 with merged phases), stage t+2 ----
// LDS swizzle as r6-r17 (0 conflicts): logical k-slot = ks*4+(lane>>4),
// physical = logical ^ (lane&7); linear gload_lds dest + pre-swizzled source.
#define LOAD_A(DST, BUFI, MH)                                                     \
    UNROLL for (int mf = 0; mf < 4; ++mf)                                         \
        UNROLL for (int ks = 0; ks < 2; ++ks)                                     \
            DST[mf][ks] = *reinterpret_cast<const bf16x8*>(                       \
                &sA[BUFI][((MH)*128 + arow_base + mf*16)*BK +                     \
                          (((ks*4 + rslot_hi) ^ rslot_xor)*8)]);

#define LOAD_B(DST, BUFI, NH)                                                     \
    UNROLL for (int nf = 0; nf < 2; ++nf)                                         \
        UNROLL for (int ks = 0; ks < 2; ++ks)                                     \
            DST[nf][ks] = *reinterpret_cast<const bf16x8*>(                       \
                &sB[BUFI][((NH)*128 + brow_base + nf*16)*BK +                     \
                          (((ks*4 + rslot_hi) ^ rslot_xor)*8)]);

#define MFMA_Q(MH, NH, AR, BR)                                                    \
    UNROLL for (int mf = 0; mf < 4; ++mf)                                         \
        UNROLL for (int nf = 0; nf < 2; ++nf) {                                   \
            acc[MH][mf][NH][nf] = __builtin_amdgcn_mfma_f32_16x16x32_bf16(        \
                AR[mf][0], BR[nf][0], acc[MH][mf][NH][nf], 0, 0, 0);              \
            acc[MH][mf][NH][nf] = __builtin_amdgcn_mfma_f32_16x16x32_bf16(        \
                AR[mf][1], BR[nf][1], acc[MH][mf][NH][nf], 0, 0, 0);              \
        }

// phase-end: own-wave LDS drain (reads consumed by this phase's MFMAs -> cheap),
// barrier (publishes reads-complete for WAR-safe staging), fence (no hoisting).
#define PH_BAR()                                                                  \
    asm volatile("s_waitcnt lgkmcnt(0)" ::: "memory");                            \
    __builtin_amdgcn_s_barrier();                                                 \
    asm volatile("" ::: "memory");

// One K-tile (buf BUF), TWO phases.
//  P1: q00,q01 on reads A0(8)+B0(4)+B1(4); stage Ah1(AH1T) -> BUF^1 (completes
//      tile t+1; its slot was published at the gate -> WAR-safe).
//  P2: q11,q10 on read A1(8); stage Ah0,Bh0,Bh1 of TS -> BUF (those slots died
//      at P1's barrier).
#define TILE2(BUF, AH1T, TS)                                                      \
    LOAD_A(a_r, BUF, 0); LOAD_B(b0_r, BUF, 0); LOAD_B(b1_r, BUF, 1);              \
    if ((AH1T) >= 0) { stA(1,0,AH1T,(BUF)^1); stA(1,1,AH1T,(BUF)^1); }            \
    __builtin_amdgcn_s_setprio(1);                                                \
    MFMA_Q(0, 0, a_r, b0_r);                                                      \
    MFMA_Q(0, 1, a_r, b1_r);                                                      \
    __builtin_amdgcn_s_setprio(0);                                                \
    PH_BAR();                                                                     \
    LOAD_A(a_r, BUF, 1);                                                          \
    if ((TS) >= 0) { stA(0,0,TS,BUF); stA(0,1,TS,BUF);                            \
                     stB(0,0,TS,BUF); stB(0,1,TS,BUF);                            \
                     stB(1,0,TS,BUF); stB(1,1,TS,BUF); }                          \
    __builtin_amdgcn_s_setprio(1);                                                \
    MFMA_Q(1, 1, a_r, b1_r);                                                      \
    MFMA_Q(1, 0, a_r, b0_r);                                                      \
    __builtin_amdgcn_s_setprio(0);

// tile-end gate: own LDS drain + wait all but the newest VMN stages + barrier.
#define GATE(VMN)                                                                 \
    asm volatile("s_waitcnt lgkmcnt(0) vmcnt(" #VMN ")" ::: "memory");            \
    __builtin_amdgcn_s_barrier();                                                 \
    asm volatile("" ::: "memory");

__global__ __launch_bounds__(512, 2) void gemm_p2_kernel(
        const unsigned short* __restrict__ A,   // [M][K] bf16
        const unsigned short* __restrict__ B,   // [N][K] bf16
        const float* __restrict__ bias,         // [N]
        float* __restrict__ C) {                // [M][N] f32
    __shared__ __align__(16) unsigned short sA[2][BM * BK];   // 2 x 32 KB
    __shared__ __align__(16) unsigned short sB[2][BN * BK];   // 2 x 32 KB

    // XCD swizzle (nwg = 2048, % 8 == 0 -> bijective)
    const int nwg = gridDim.x;
    const int bid = blockIdx.x;
    const int wg  = (bid & 7) * (nwg >> 3) + (bid >> 3);
    const int nbn = N_TOTAL / BN;            // 64
    const int brow = (wg / nbn) * BM;
    const int bcol = (wg % nbn) * BN;

    const int tid  = threadIdx.x;
    const int wid  = tid >> 6;               // 0..7
    const int lane = tid & 63;
    const int wm   = wid >> 2;               // 0..1  (M-waves)
    const int wn   = wid & 3;                // 0..3  (N-waves)

    // staging: linear LDS dest + pre-swizzled global source (rule #21)
    const int srow = wid * 8 + (lane >> 3);
    const int scol = ((lane & 7) ^ (lane >> 3)) * 8;
    const unsigned short* Asrc = A + (long long)(brow + srow) * K_TOTAL + scol;
    const unsigned short* Bsrc = B + (long long)(bcol + srow) * K_TOTAL + scol;

    auto stA = [&](int h, int j, int kt, int b) {
        gload_lds16(Asrc + (long long)(h*128 + j*64) * K_TOTAL + kt*BK,
                    &sA[b][(h*128 + j*64)*BK + wid*512]);
    };
    auto stB = [&](int h, int j, int kt, int b) {
        gload_lds16(Bsrc + (long long)(h*128 + j*64) * K_TOTAL + kt*BK,
                    &sB[b][(h*128 + j*64)*BK + wid*512]);
    };

    // ds-read constants (swizzled read side)
    const int arow_base = wm * 64 + (lane & 15);   // + mh*128 + mf*16
    const int brow_base = wn * 32 + (lane & 15);   // + nh*128 + nf*16
    const int rslot_hi  = lane >> 4;
    const int rslot_xor = lane & 7;

    f32x4 acc[2][4][2][2];
    UNROLL for (int mh = 0; mh < 2; ++mh)
        UNROLL for (int mf = 0; mf < 4; ++mf)
            UNROLL for (int nh = 0; nh < 2; ++nh)
                UNROLL for (int nf = 0; nf < 2; ++nf)
                    acc[mh][mf][nh][nf] = (f32x4){0.f, 0.f, 0.f, 0.f};

    bf16x8 a_r[4][2];                 // current A half (A0 in P1, A1 in P2)
    bf16x8 b0_r[2][2], b1_r[2][2];    // B half0 / half1 (tile-resident)

    // ---- prologue: tile0 full (8) -> buf0; tile1 partial {Ah0,Bh0,Bh1} (6) -> buf1
    stA(0,0,0,0); stA(0,1,0,0); stA(1,0,0,0); stA(1,1,0,0);
    stB(0,0,0,0); stB(0,1,0,0); stB(1,0,0,0); stB(1,1,0,0);
    stA(0,0,1,1); stA(0,1,1,1);
    stB(0,0,1,1); stB(0,1,1,1); stB(1,0,1,1); stB(1,1,1,1);
    asm volatile("s_waitcnt vmcnt(6)" ::: "memory");   // tile0 landed
    __builtin_amdgcn_s_barrier();
    asm volatile("" ::: "memory");

    // ---- main loop: t = 0..61 (Ah1 of t+1 staged in tile t's P1; 6 of t+2 in P2)
    for (int it = 0; it < NKT/2 - 1; ++it) {          // 31 iterations
        const int t0 = 2*it;
        TILE2(0, t0 + 1, t0 + 2)
        GATE(6)
        TILE2(1, t0 + 2, t0 + 3)
        GATE(6)
    }
    // t = 62: stage Ah1(63); no 6-stage; then drain everything
    TILE2(0, 63, -1)
    GATE(0)
    // t = 63: nothing left to stage
    TILE2(1, -1, -1)

    // ---- epilogue: C/D layout col = lane&15, row = (lane>>4)*4 + r ----
    const int crow0 = (lane >> 4) * 4;
    const int ccol  = lane & 15;
    UNROLL for (int mh = 0; mh < 2; ++mh)
        UNROLL for (int mf = 0; mf < 4; ++mf) {
            const long long row0 = (long long)brow + mh*128 + wm*64 + mf*16 + crow0;
            UNROLL for (int nh = 0; nh < 2; ++nh)
                UNROLL for (int nf = 0; nf < 2; ++nf) {
                    const int col = bcol + nh*128 + wn*32 + nf*16 + ccol;
                    const float bv = bias[col];
                    UNROLL for (int r = 0; r < 4; ++r)
                        C[(row0 + r) * N_TOTAL + col] = acc[mh][mf][nh][nf][r] + bv;
                }
        }
}

extern "C" void kernel_launch(void* const* d_in, const int* in_sizes, int n_in,
                              void* d_out, int out_size, void* d_ws, size_t ws_size,
                              hipStream_t stream) {
    const float* x      = (const float*)d_in[0];   // [4,2048,4096] f32
    const int*   wq     = (const int*)  d_in[1];   // [16384,4096] int32 idx
    const float* absmax = (const float*)d_in[2];   // [16384]
    const float* code   = (const float*)d_in[3];   // [256]
    const float* bias   = (const float*)d_in[4];   // [16384]
    float* out = (float*)d_out;                    // [4,2048,16384] f32

    unsigned short* wb = (unsigned short*)d_ws;                    // W bf16 134 MB
    unsigned short* xb = wb + (size_t)N_TOTAL * K_TOTAL;           // x bf16  67 MB

    dequant_w_kernel<<<2048, 256, 0, stream>>>(wq, absmax, code, wb);
    cvt_x_kernel   <<<2048, 256, 0, stream>>>(x, xb);

    dim3 grid((M_TOTAL / BM) * (N_TOTAL / BN));    // 32*64 = 2048 blocks
    gemm_p2_kernel<<<grid, 512, 0, stream>>>(xb, wb, bias, out);
}